// Round 7
// baseline (498.138 us; speedup 1.0000x reference)
//
#include <hip/hip_runtime.h>
#include <stdint.h>
#include <math.h>

// QLoRA linear: out = x @ (scale*qweight^T) + bias + (x@A)@B
// M=8192, N=4096, K=4096, RANK=16.
//
// R8: (1) gemm ring-3 -> ring-4 (128 KB LDS), steady vmcnt(12): 3 K-tiles
//     in flight (+50% MLP; R7 sat at 4.8 TB/s service = latency x MLP
//     equilibrium, while R6 proved >=7.7 TB/s is available).
//     (2) out stores via __builtin_nontemporal_store (write-once stream was
//     thrashing X/W out of L3: FETCH 149 MB vs 50 MB ideal).
//     Keeps: 256^2 tile / 512 thr (R7: traffic 2.15->1.07 GB, gemm -54us),
//     conflict-free [q][row][16B] LDS, XCD swizzle, setprio.
//     prep/xa unchanged.

static constexpr int Mdim = 8192;
static constexpr int Ndim = 4096;
static constexpr int Kdim = 4096;

typedef __bf16 bf16x8 __attribute__((ext_vector_type(8)));
typedef float f32x4 __attribute__((ext_vector_type(4)));
typedef int   i32x4 __attribute__((ext_vector_type(4)));

__device__ __forceinline__ void async_copy16(const void* gptr, void* lptr) {
    auto g = (const __attribute__((address_space(1))) unsigned char*)(uintptr_t)gptr;
    auto l = (__attribute__((address_space(3))) unsigned char*)(uintptr_t)lptr;
    __builtin_amdgcn_global_load_lds(g, l, 16, 0, 0);
}

#define ASM_VMCNT12 asm volatile("s_waitcnt vmcnt(12)" ::: "memory")
#define ASM_VMCNT8  asm volatile("s_waitcnt vmcnt(8)" ::: "memory")
#define ASM_VMCNT4  asm volatile("s_waitcnt vmcnt(4)" ::: "memory")
#define ASM_VMCNT0  asm volatile("s_waitcnt vmcnt(0)" ::: "memory")

// ---------------- prep: 4 roles by blockIdx ----------------
static constexpr int BLK_W = Ndim * Kdim / (256 * 16);  // 4096
static constexpr int BLK_X = Mdim;                      // 8192
static constexpr int BLK_BT = Ndim / 256;               // 16

__global__ void __launch_bounds__(256) prep_kernel(
        const float* __restrict__ x,
        const int* __restrict__ qw,
        const float* __restrict__ lA,   // [K][16]
        const float* __restrict__ lB,   // [16][N]
        int8_t* __restrict__ x_i8,      // [M][K]
        int8_t* __restrict__ w_i8,      // [N][K]
        int8_t* __restrict__ a_i8t,     // [16][K]
        __bf16* __restrict__ Blbt,      // [N][16]
        float* __restrict__ row_scale,  // [M]
        float* __restrict__ a_scale_g,
        float* __restrict__ xabf) {     // [M][16] f32 accumulator (zeroed here)
    __shared__ float red[8];
    int b = blockIdx.x;
    const int tid = threadIdx.x;

    if (b == 0) {
        // ---- role A: quantize lora_A -> a_i8t[16][K] (transposed) ----
        float am = 0.f;
        const float4* ap = (const float4*)lA + tid * 64;  // 256 floats/thread
        for (int i = 0; i < 64; ++i) {
            float4 v = ap[i];
            am = fmaxf(am, fmaxf(fmaxf(fabsf(v.x), fabsf(v.y)),
                                 fmaxf(fabsf(v.z), fabsf(v.w))));
        }
        for (int off = 32; off; off >>= 1) am = fmaxf(am, __shfl_xor(am, off));
        if ((tid & 63) == 0) red[tid >> 6] = am;
        __syncthreads();
        if (tid == 0) {
            float m = fmaxf(fmaxf(red[0], red[1]), fmaxf(red[2], red[3]));
            red[4] = m;
            a_scale_g[0] = m > 0.f ? m / 127.f : 0.f;
        }
        __syncthreads();
        float amax = red[4];
        float inv = amax > 0.f ? 127.f / amax : 0.f;
        int k0 = tid * 16;
#pragma unroll
        for (int r = 0; r < 16; ++r) {
            int8_t o[16];
#pragma unroll
            for (int kk = 0; kk < 16; ++kk) {
                float v = lA[(size_t)(k0 + kk) * 16 + r];
                o[kk] = (int8_t)(int)rintf(v * inv);
            }
            *(i32x4*)(a_i8t + (size_t)r * Kdim + k0) = *(i32x4*)o;
        }
        return;
    }
    b -= 1;

    if (b < BLK_W) {
        // ---- role W: qweight int32 -> int8 ----
        size_t idx = ((size_t)b * 256 + tid) * 16;
        const int4* q = (const int4*)(qw + idx);
        int4 q0 = q[0], q1 = q[1], q2 = q[2], q3 = q[3];
        int8_t o[16] = {(int8_t)q0.x, (int8_t)q0.y, (int8_t)q0.z, (int8_t)q0.w,
                        (int8_t)q1.x, (int8_t)q1.y, (int8_t)q1.z, (int8_t)q1.w,
                        (int8_t)q2.x, (int8_t)q2.y, (int8_t)q2.z, (int8_t)q2.w,
                        (int8_t)q3.x, (int8_t)q3.y, (int8_t)q3.z, (int8_t)q3.w};
        *(i32x4*)(w_i8 + idx) = *(i32x4*)o;
        return;
    }
    b -= BLK_W;

    if (b < BLK_X) {
        // ---- role X: per-row int8 quant of x ----
        const int row = b;
        const float4* xp = (const float4*)(x + (size_t)row * Kdim) + tid * 4;
        float4 v0 = xp[0], v1 = xp[1], v2 = xp[2], v3 = xp[3];
        float am = 0.f;
        am = fmaxf(am, fmaxf(fmaxf(fabsf(v0.x), fabsf(v0.y)), fmaxf(fabsf(v0.z), fabsf(v0.w))));
        am = fmaxf(am, fmaxf(fmaxf(fabsf(v1.x), fabsf(v1.y)), fmaxf(fabsf(v1.z), fabsf(v1.w))));
        am = fmaxf(am, fmaxf(fmaxf(fabsf(v2.x), fabsf(v2.y)), fmaxf(fabsf(v2.z), fabsf(v2.w))));
        am = fmaxf(am, fmaxf(fmaxf(fabsf(v3.x), fabsf(v3.y)), fmaxf(fabsf(v3.z), fabsf(v3.w))));
        for (int off = 32; off; off >>= 1) am = fmaxf(am, __shfl_xor(am, off));
        if ((tid & 63) == 0) red[tid >> 6] = am;
        __syncthreads();
        if (tid == 0) {
            float m = fmaxf(fmaxf(red[0], red[1]), fmaxf(red[2], red[3]));
            red[4] = m;
            row_scale[row] = m > 0.f ? m / 127.f : 0.f;
        }
        __syncthreads();
        float amax = red[4];
        float inv = amax > 0.f ? 127.f / amax : 0.f;
        float vv[16] = {v0.x, v0.y, v0.z, v0.w, v1.x, v1.y, v1.z, v1.w,
                        v2.x, v2.y, v2.z, v2.w, v3.x, v3.y, v3.z, v3.w};
        int8_t o[16];
#pragma unroll
        for (int i = 0; i < 16; ++i) o[i] = (int8_t)(int)rintf(vv[i] * inv);
        *(i32x4*)(x_i8 + (size_t)row * Kdim + tid * 16) = *(i32x4*)o;
        return;
    }
    b -= BLK_X;

    {
        // ---- role Bt: lora_B transpose -> bf16 [N][16], plus zero xabf ----
        int c = b * 256 + tid;
        __bf16 tmp[16];
#pragma unroll
        for (int r = 0; r < 16; ++r) tmp[r] = (__bf16)lB[(size_t)r * Ndim + c];
        *(bf16x8*)(Blbt + (size_t)c * 16) = *(bf16x8*)tmp;
        *(bf16x8*)(Blbt + (size_t)c * 16 + 8) = *(bf16x8*)(tmp + 8);
        // zero the f32 xA accumulator: 16 blocks * 256 thr * 32 floats = M*16
        f32x4 z = {0.f, 0.f, 0.f, 0.f};
        f32x4* zp = (f32x4*)(xabf + (size_t)(b * 256 + tid) * 32);
#pragma unroll
        for (int i = 0; i < 8; ++i) zp[i] = z;
    }
}

// ---------------- xA = x_i8 @ A_i8^T -> f32 atomics [M][16] ----------------
// 512 blocks: (bm 0..127) x (kc 0..3); each handles 64 rows x 1024 K, dbuf.
__global__ void __launch_bounds__(256) xa_kernel(
        const int8_t* __restrict__ x_i8,
        const int8_t* __restrict__ a_i8t,
        const float* __restrict__ row_scale,
        const float* __restrict__ a_scale_g,
        float* __restrict__ xabf) {
    __shared__ __align__(16) char sX[2][4096];   // [q 4][row 64][16B]
    __shared__ __align__(16) char sAq[2][1024];  // [q 4][row 16][16B]
    const int tid = threadIdx.x, wave = tid >> 6, lane = tid & 63;
    const int quad = lane >> 4, l16 = lane & 15;
    const int bm = blockIdx.x >> 2;
    const int kc = blockIdx.x & 3;
    const int kbeg = kc * (Kdim / 4);

    // staging: slot s=tid -> (q = tid>>6, row = tid&63) for X
    const size_t xoff = (size_t)(bm * 64 + (tid & 63)) * Kdim + (tid >> 6) * 16;
    // A: 64 slots: (q = tid>>4, row = tid&15)
    const size_t aoff = (size_t)(tid & 15) * Kdim + (tid >> 4) * 16;

    i32x4 acc = {0, 0, 0, 0};
    async_copy16(x_i8 + xoff + kbeg, sX[0] + tid * 16);
    if (tid < 64) async_copy16(a_i8t + aoff + kbeg, sAq[0] + tid * 16);
    __syncthreads();
    int cur = 0;
    const int rdA = (quad * 64 + wave * 16 + l16) * 16;
    const int rdB = (quad * 16 + l16) * 16;
#pragma unroll 1
    for (int t = 0; t < 16; ++t) {
        if (t < 15) {
            async_copy16(x_i8 + xoff + kbeg + (t + 1) * 64, sX[cur ^ 1] + tid * 16);
            if (tid < 64)
                async_copy16(a_i8t + aoff + kbeg + (t + 1) * 64, sAq[cur ^ 1] + tid * 16);
        }
        i32x4 af = *(const i32x4*)(sX[cur] + rdA);
        i32x4 bf = *(const i32x4*)(sAq[cur] + rdB);
        acc = __builtin_amdgcn_mfma_i32_16x16x64_i8(af, bf, acc, 0, 0, 0);
        __syncthreads();
        cur ^= 1;
    }
    const float asc = a_scale_g[0];
    const int rl = wave * 16 + quad * 4;
#pragma unroll
    for (int r = 0; r < 4; ++r) {
        int grow = bm * 64 + rl + r;
        float v = (float)acc[r] * row_scale[grow] * asc;
        atomicAdd(xabf + (size_t)grow * 16 + l16, v);
    }
}

// ---------------- main GEMM: 256x256 tile, 512 thr, 4-buffer ring ----------------
__global__ void __launch_bounds__(512, 2) gemm_kernel(
        const int8_t* __restrict__ Xq,       // [M][K]
        const int8_t* __restrict__ Wq,       // [N][K]
        const float* __restrict__ scales,    // [1]
        const float* __restrict__ bias,      // [N]
        const float* __restrict__ row_scale, // [M]
        const float* __restrict__ xabf,      // [M][16] f32
        const __bf16* __restrict__ Blbt,     // [N][16]
        float* __restrict__ out) {           // [M][N]
    // ring: R0@0, R1@32K, R2@64K, R3@96K. Each: A [q4][row256][16B] (16KB)
    // then B same (16KB). Total 128 KB -> 1 block/CU.
    __shared__ __align__(16) char smem[131072];

    const int tid = threadIdx.x;             // 0..511
    const int wave = tid >> 6, lane = tid & 63;
    const int wm = wave >> 2, wn = wave & 3; // 2 x 4 wave grid
    const int quad = lane >> 4, l16 = lane & 15;

    // XCD swizzle: 512 blocks, 64/XCD; each XCD = contiguous 4-bm stripe x 16 bn
    const int bid = blockIdx.y * gridDim.x + blockIdx.x;  // 0..511
    const int xcd = bid & 7;
    const int local = bid >> 3;                           // 0..63
    const int bm = xcd * 4 + (local >> 4);                // 0..31
    const int bn = local & 15;                            // 0..15

    // staging: per thread 2 slots per operand. slot c: q = c*2 + (tid>>8),
    // row = tid & 255; LDS dst = q*4096 + row*16 = c*8192 + tid*16 (linear).
    const size_t a_base0 = (size_t)(bm * 256 + (tid & 255)) * Kdim + (tid >> 8) * 16;
    const size_t a_base1 = a_base0 + 32;
    const size_t b_base0 = (size_t)(bn * 256 + (tid & 255)) * Kdim + (tid >> 8) * 16;
    const size_t b_base1 = b_base0 + 32;
    const int dst0 = tid * 16, dst1 = 8192 + tid * 16;

    // ds_read bases: addr = q*4096 + row*16 (+ frag*256)
    const int qplane = quad * 4096;
    const int arowb = (wm * 128 + l16) * 16;
    const int browb = (wn * 64 + l16) * 16;

    i32x4 acc[8][4];
#pragma unroll
    for (int i = 0; i < 8; ++i)
#pragma unroll
        for (int j = 0; j < 4; ++j) acc[i][j] = i32x4{0, 0, 0, 0};

    char* const R0 = smem;
    char* const R1 = smem + 32768;
    char* const R2 = smem + 65536;
    char* const R3 = smem + 98304;

    auto stage = [&](int k0, char* buf) {
        char* PB = buf + 16384;
        async_copy16(Xq + a_base0 + k0, buf + dst0);
        async_copy16(Xq + a_base1 + k0, buf + dst1);
        async_copy16(Wq + b_base0 + k0, PB + dst0);
        async_copy16(Wq + b_base1 + k0, PB + dst1);
    };
    auto compute = [&](const char* buf) {
        const char* PB = buf + 16384;
#pragma unroll
        for (int qd = 0; qd < 4; ++qd) {
            const int i0 = (qd & 1) * 4, j0 = (qd >> 1) * 2;
            i32x4 aF[4], bF[2];
#pragma unroll
            for (int ii = 0; ii < 4; ++ii)
                aF[ii] = *(const i32x4*)(buf + qplane + arowb + (i0 + ii) * 256);
#pragma unroll
            for (int jj = 0; jj < 2; ++jj)
                bF[jj] = *(const i32x4*)(PB + qplane + browb + (j0 + jj) * 256);
            __builtin_amdgcn_s_setprio(1);
#pragma unroll
            for (int ii = 0; ii < 4; ++ii)
#pragma unroll
                for (int jj = 0; jj < 2; ++jj)
                    acc[i0 + ii][j0 + jj] = __builtin_amdgcn_mfma_i32_16x16x64_i8(
                        aF[ii], bF[jj], acc[i0 + ii][j0 + jj], 0, 0, 0);
            __builtin_amdgcn_s_setprio(0);
        }
    };

    // 64 K-tiles of 64. Prologue: tiles 0,1,2 into R0,R1,R2.
    stage(0, R0);
    stage(64, R1);
    stage(128, R2);
#pragma unroll 1
    for (int u = 0; u < 15; ++u) {         // tiles 4u .. 4u+3 (0..59)
        const int k = u * 256;
        stage(k + 192, R3);                // tile 4u+3
        ASM_VMCNT12;                       // tile 4u landed; 3 tiles in flight
        __builtin_amdgcn_s_barrier();
        compute(R0);                       // tile 4u
        __builtin_amdgcn_s_barrier();
        stage(k + 256, R0);                // tile 4u+4
        ASM_VMCNT12;
        __builtin_amdgcn_s_barrier();
        compute(R1);                       // tile 4u+1
        __builtin_amdgcn_s_barrier();
        stage(k + 320, R1);                // tile 4u+5
        ASM_VMCNT12;
        __builtin_amdgcn_s_barrier();
        compute(R2);                       // tile 4u+2
        __builtin_amdgcn_s_barrier();
        stage(k + 384, R2);                // tile 4u+6
        ASM_VMCNT12;
        __builtin_amdgcn_s_barrier();
        compute(R3);                       // tile 4u+3
        __builtin_amdgcn_s_barrier();
    }
    // computed through 59; staged through 62 (u=14 staged 4*14+6=62 into R2)
    stage(63 * 64, R3);                    // tile 63
    ASM_VMCNT12;
    __builtin_amdgcn_s_barrier();
    compute(R0);                           // tile 60
    __builtin_amdgcn_s_barrier();
    ASM_VMCNT8;
    __builtin_amdgcn_s_barrier();
    compute(R1);                           // tile 61
    __builtin_amdgcn_s_barrier();
    ASM_VMCNT4;
    __builtin_amdgcn_s_barrier();
    compute(R2);                           // tile 62
    __builtin_amdgcn_s_barrier();
    ASM_VMCNT0;
    __builtin_amdgcn_s_barrier();
    compute(R3);                           // tile 63

    // -------- epilogue: lora (bf16 MFMA, K=16 zero-padded) + bias + dequant --------
    const float wsc = scales[0];
    float bj4[4];
#pragma unroll
    for (int j = 0; j < 4; ++j) bj4[j] = bias[bn * 256 + wn * 64 + j * 16 + l16];

    __syncthreads();  // all waves done with LDS
    // sXAf [256][16] f32 @0 (16KB); sBL bf16 [256][16] @16384 (8KB); sRS @24576 (1KB)
    async_copy16((const char*)xabf + (size_t)bm * 256 * 64 + tid * 16, smem + tid * 16);
    async_copy16((const char*)xabf + (size_t)bm * 256 * 64 + 8192 + tid * 16,
                 smem + 8192 + tid * 16);
    async_copy16((const char*)(Blbt + (size_t)bn * 256 * 16) + tid * 16,
                 smem + 16384 + tid * 16);
    if (tid < 64)
        async_copy16((const char*)(row_scale + bm * 256) + tid * 16,
                     smem + 24576 + tid * 16);
    __syncthreads();

    const float*  sXAf = (const float*)smem;            // [256][16]
    const __bf16* sBL  = (const __bf16*)(smem + 16384); // [256 cols][16]
    const float*  sRS  = (const float*)(smem + 24576);  // [256]

    bf16x8 zf;
#pragma unroll
    for (int k = 0; k < 8; ++k) zf[k] = (__bf16)0.f;

    bf16x8 aF2[8], bF2[4];
#pragma unroll
    for (int i = 0; i < 8; ++i) {
        if (quad < 2) {
            const float* p = sXAf + (wm * 128 + i * 16 + l16) * 16 + quad * 8;
            f32x4 u0 = *(const f32x4*)p;
            f32x4 u1 = *(const f32x4*)(p + 4);
            bf16x8 t;
            t[0] = (__bf16)u0[0]; t[1] = (__bf16)u0[1];
            t[2] = (__bf16)u0[2]; t[3] = (__bf16)u0[3];
            t[4] = (__bf16)u1[0]; t[5] = (__bf16)u1[1];
            t[6] = (__bf16)u1[2]; t[7] = (__bf16)u1[3];
            aF2[i] = t;
        } else {
            aF2[i] = zf;
        }
    }
#pragma unroll
    for (int j = 0; j < 4; ++j) {
        if (quad < 2) bF2[j] = *(const bf16x8*)(sBL + (wn * 64 + j * 16 + l16) * 16 + quad * 8);
        else          bF2[j] = zf;
    }

    const int col0 = bn * 256 + wn * 64 + l16;
#pragma unroll
    for (int i = 0; i < 8; ++i) {
#pragma unroll
        for (int j = 0; j < 4; ++j) {
            f32x4 l = f32x4{bj4[j], bj4[j], bj4[j], bj4[j]};
            l = __builtin_amdgcn_mfma_f32_16x16x32_bf16(aF2[i], bF2[j], l, 0, 0, 0);
            const int col = col0 + j * 16;
            const int lr = wm * 128 + i * 16 + quad * 4;  // row in block-tile
#pragma unroll
            for (int r = 0; r < 4; ++r) {
                float sx = sRS[lr + r] * wsc;
                float v = (float)acc[i][j][r] * sx + l[r];
                __builtin_nontemporal_store(
                    v, &out[(size_t)(bm * 256 + lr + r) * Ndim + col]);
            }
        }
    }
}

extern "C" void kernel_launch(void* const* d_in, const int* in_sizes, int n_in,
                              void* d_out, int out_size, void* d_ws, size_t ws_size,
                              hipStream_t stream) {
    const float* x      = (const float*)d_in[0];
    const int*   qw     = (const int*)d_in[1];
    const float* scales = (const float*)d_in[2];
    const float* bias   = (const float*)d_in[3];
    const float* lA     = (const float*)d_in[4];
    const float* lB     = (const float*)d_in[5];
    float* out = (float*)d_out;

    char* ws = (char*)d_ws;
    int8_t* x_i8     = (int8_t*)ws;                     // 33.55 MB
    int8_t* w_i8     = (int8_t*)(ws + 33554432);        // 16.78 MB
    int8_t* a_i8t    = (int8_t*)(ws + 50331648);        // 64 KB
    float*  xabf     = (float*)(ws + 50397184);         // 512 KB f32 [M][16]
    __bf16* Blbt     = (__bf16*)(ws + 50921472);        // 128 KB
    float*  row_scale = (float*)(ws + 51052544);        // 32 KB
    float*  a_scale_g = (float*)(ws + 51085312);        // 4 B

    const int prep_blocks = 1 + BLK_W + BLK_X + BLK_BT;  // 12305
    prep_kernel<<<prep_blocks, 256, 0, stream>>>(
        x, qw, lA, lB, x_i8, w_i8, a_i8t, Blbt, row_scale, a_scale_g, xabf);
    xa_kernel<<<512, 256, 0, stream>>>(x_i8, a_i8t, row_scale, a_scale_g, xabf);
    dim3 grid(Ndim / 256, Mdim / 256);                   // 16 x 32 = 512 blocks
    gemm_kernel<<<grid, 512, 0, stream>>>(x_i8, w_i8, scales, bias, row_scale,
                                          xabf, Blbt, out);
}

// Round 8
// 486.671 us; speedup vs baseline: 1.0236x; 1.0236x over previous
//
#include <hip/hip_runtime.h>
#include <stdint.h>
#include <math.h>

// QLoRA linear: out = x @ (scale*qweight^T) + bias + (x@A)@B
// M=8192, N=4096, K=4096, RANK=16.
//
// R9: 256^2 tile KEPT (R7: traffic 2.15->1.07 GB) but LDS cut to 64 KB
//   double-buffer -> 2 blocks/CU. R6 vs R7/R8 isolated the mechanism: at
//   equal waves/CU, TWO independent barrier groups sustain 7.8 TB/s staging
//   service; ONE lockstep group only 4.6-4.8 (nothing covers the per-step
//   vmcnt+barrier drain). Ring depth >2 within one block was null (R8).
//   NT stores reverted (R8: WRITE_SIZE 131->178 MB, worse).
//   Schedule: R6's 2-step unrolled counted-vmcnt(4), static buffer names.
//   prep/xa unchanged.

static constexpr int Mdim = 8192;
static constexpr int Ndim = 4096;
static constexpr int Kdim = 4096;

typedef __bf16 bf16x8 __attribute__((ext_vector_type(8)));
typedef float f32x4 __attribute__((ext_vector_type(4)));
typedef int   i32x4 __attribute__((ext_vector_type(4)));

__device__ __forceinline__ void async_copy16(const void* gptr, void* lptr) {
    auto g = (const __attribute__((address_space(1))) unsigned char*)(uintptr_t)gptr;
    auto l = (__attribute__((address_space(3))) unsigned char*)(uintptr_t)lptr;
    __builtin_amdgcn_global_load_lds(g, l, 16, 0, 0);
}

#define ASM_VMCNT4  asm volatile("s_waitcnt vmcnt(4)" ::: "memory")
#define ASM_VMCNT0  asm volatile("s_waitcnt vmcnt(0)" ::: "memory")

// ---------------- prep: 4 roles by blockIdx ----------------
static constexpr int BLK_W = Ndim * Kdim / (256 * 16);  // 4096
static constexpr int BLK_X = Mdim;                      // 8192
static constexpr int BLK_BT = Ndim / 256;               // 16

__global__ void __launch_bounds__(256) prep_kernel(
        const float* __restrict__ x,
        const int* __restrict__ qw,
        const float* __restrict__ lA,   // [K][16]
        const float* __restrict__ lB,   // [16][N]
        int8_t* __restrict__ x_i8,      // [M][K]
        int8_t* __restrict__ w_i8,      // [N][K]
        int8_t* __restrict__ a_i8t,     // [16][K]
        __bf16* __restrict__ Blbt,      // [N][16]
        float* __restrict__ row_scale,  // [M]
        float* __restrict__ a_scale_g,
        float* __restrict__ xabf) {     // [M][16] f32 accumulator (zeroed here)
    __shared__ float red[8];
    int b = blockIdx.x;
    const int tid = threadIdx.x;

    if (b == 0) {
        // ---- role A: quantize lora_A -> a_i8t[16][K] (transposed) ----
        float am = 0.f;
        const float4* ap = (const float4*)lA + tid * 64;  // 256 floats/thread
        for (int i = 0; i < 64; ++i) {
            float4 v = ap[i];
            am = fmaxf(am, fmaxf(fmaxf(fabsf(v.x), fabsf(v.y)),
                                 fmaxf(fabsf(v.z), fabsf(v.w))));
        }
        for (int off = 32; off; off >>= 1) am = fmaxf(am, __shfl_xor(am, off));
        if ((tid & 63) == 0) red[tid >> 6] = am;
        __syncthreads();
        if (tid == 0) {
            float m = fmaxf(fmaxf(red[0], red[1]), fmaxf(red[2], red[3]));
            red[4] = m;
            a_scale_g[0] = m > 0.f ? m / 127.f : 0.f;
        }
        __syncthreads();
        float amax = red[4];
        float inv = amax > 0.f ? 127.f / amax : 0.f;
        int k0 = tid * 16;
#pragma unroll
        for (int r = 0; r < 16; ++r) {
            int8_t o[16];
#pragma unroll
            for (int kk = 0; kk < 16; ++kk) {
                float v = lA[(size_t)(k0 + kk) * 16 + r];
                o[kk] = (int8_t)(int)rintf(v * inv);
            }
            *(i32x4*)(a_i8t + (size_t)r * Kdim + k0) = *(i32x4*)o;
        }
        return;
    }
    b -= 1;

    if (b < BLK_W) {
        // ---- role W: qweight int32 -> int8 ----
        size_t idx = ((size_t)b * 256 + tid) * 16;
        const int4* q = (const int4*)(qw + idx);
        int4 q0 = q[0], q1 = q[1], q2 = q[2], q3 = q[3];
        int8_t o[16] = {(int8_t)q0.x, (int8_t)q0.y, (int8_t)q0.z, (int8_t)q0.w,
                        (int8_t)q1.x, (int8_t)q1.y, (int8_t)q1.z, (int8_t)q1.w,
                        (int8_t)q2.x, (int8_t)q2.y, (int8_t)q2.z, (int8_t)q2.w,
                        (int8_t)q3.x, (int8_t)q3.y, (int8_t)q3.z, (int8_t)q3.w};
        *(i32x4*)(w_i8 + idx) = *(i32x4*)o;
        return;
    }
    b -= BLK_W;

    if (b < BLK_X) {
        // ---- role X: per-row int8 quant of x ----
        const int row = b;
        const float4* xp = (const float4*)(x + (size_t)row * Kdim) + tid * 4;
        float4 v0 = xp[0], v1 = xp[1], v2 = xp[2], v3 = xp[3];
        float am = 0.f;
        am = fmaxf(am, fmaxf(fmaxf(fabsf(v0.x), fabsf(v0.y)), fmaxf(fabsf(v0.z), fabsf(v0.w))));
        am = fmaxf(am, fmaxf(fmaxf(fabsf(v1.x), fabsf(v1.y)), fmaxf(fabsf(v1.z), fabsf(v1.w))));
        am = fmaxf(am, fmaxf(fmaxf(fabsf(v2.x), fabsf(v2.y)), fmaxf(fabsf(v2.z), fabsf(v2.w))));
        am = fmaxf(am, fmaxf(fmaxf(fabsf(v3.x), fabsf(v3.y)), fmaxf(fabsf(v3.z), fabsf(v3.w))));
        for (int off = 32; off; off >>= 1) am = fmaxf(am, __shfl_xor(am, off));
        if ((tid & 63) == 0) red[tid >> 6] = am;
        __syncthreads();
        if (tid == 0) {
            float m = fmaxf(fmaxf(red[0], red[1]), fmaxf(red[2], red[3]));
            red[4] = m;
            row_scale[row] = m > 0.f ? m / 127.f : 0.f;
        }
        __syncthreads();
        float amax = red[4];
        float inv = amax > 0.f ? 127.f / amax : 0.f;
        float vv[16] = {v0.x, v0.y, v0.z, v0.w, v1.x, v1.y, v1.z, v1.w,
                        v2.x, v2.y, v2.z, v2.w, v3.x, v3.y, v3.z, v3.w};
        int8_t o[16];
#pragma unroll
        for (int i = 0; i < 16; ++i) o[i] = (int8_t)(int)rintf(vv[i] * inv);
        *(i32x4*)(x_i8 + (size_t)row * Kdim + tid * 16) = *(i32x4*)o;
        return;
    }
    b -= BLK_X;

    {
        // ---- role Bt: lora_B transpose -> bf16 [N][16], plus zero xabf ----
        int c = b * 256 + tid;
        __bf16 tmp[16];
#pragma unroll
        for (int r = 0; r < 16; ++r) tmp[r] = (__bf16)lB[(size_t)r * Ndim + c];
        *(bf16x8*)(Blbt + (size_t)c * 16) = *(bf16x8*)tmp;
        *(bf16x8*)(Blbt + (size_t)c * 16 + 8) = *(bf16x8*)(tmp + 8);
        // zero the f32 xA accumulator: 16 blocks * 256 thr * 32 floats = M*16
        f32x4 z = {0.f, 0.f, 0.f, 0.f};
        f32x4* zp = (f32x4*)(xabf + (size_t)(b * 256 + tid) * 32);
#pragma unroll
        for (int i = 0; i < 8; ++i) zp[i] = z;
    }
}

// ---------------- xA = x_i8 @ A_i8^T -> f32 atomics [M][16] ----------------
// 512 blocks: (bm 0..127) x (kc 0..3); each handles 64 rows x 1024 K, dbuf.
__global__ void __launch_bounds__(256) xa_kernel(
        const int8_t* __restrict__ x_i8,
        const int8_t* __restrict__ a_i8t,
        const float* __restrict__ row_scale,
        const float* __restrict__ a_scale_g,
        float* __restrict__ xabf) {
    __shared__ __align__(16) char sX[2][4096];   // [q 4][row 64][16B]
    __shared__ __align__(16) char sAq[2][1024];  // [q 4][row 16][16B]
    const int tid = threadIdx.x, wave = tid >> 6, lane = tid & 63;
    const int quad = lane >> 4, l16 = lane & 15;
    const int bm = blockIdx.x >> 2;
    const int kc = blockIdx.x & 3;
    const int kbeg = kc * (Kdim / 4);

    // staging: slot s=tid -> (q = tid>>6, row = tid&63) for X
    const size_t xoff = (size_t)(bm * 64 + (tid & 63)) * Kdim + (tid >> 6) * 16;
    // A: 64 slots: (q = tid>>4, row = tid&15)
    const size_t aoff = (size_t)(tid & 15) * Kdim + (tid >> 4) * 16;

    i32x4 acc = {0, 0, 0, 0};
    async_copy16(x_i8 + xoff + kbeg, sX[0] + tid * 16);
    if (tid < 64) async_copy16(a_i8t + aoff + kbeg, sAq[0] + tid * 16);
    __syncthreads();
    int cur = 0;
    const int rdA = (quad * 64 + wave * 16 + l16) * 16;
    const int rdB = (quad * 16 + l16) * 16;
#pragma unroll 1
    for (int t = 0; t < 16; ++t) {
        if (t < 15) {
            async_copy16(x_i8 + xoff + kbeg + (t + 1) * 64, sX[cur ^ 1] + tid * 16);
            if (tid < 64)
                async_copy16(a_i8t + aoff + kbeg + (t + 1) * 64, sAq[cur ^ 1] + tid * 16);
        }
        i32x4 af = *(const i32x4*)(sX[cur] + rdA);
        i32x4 bf = *(const i32x4*)(sAq[cur] + rdB);
        acc = __builtin_amdgcn_mfma_i32_16x16x64_i8(af, bf, acc, 0, 0, 0);
        __syncthreads();
        cur ^= 1;
    }
    const float asc = a_scale_g[0];
    const int rl = wave * 16 + quad * 4;
#pragma unroll
    for (int r = 0; r < 4; ++r) {
        int grow = bm * 64 + rl + r;
        float v = (float)acc[r] * row_scale[grow] * asc;
        atomicAdd(xabf + (size_t)grow * 16 + l16, v);
    }
}

// ---------------- main GEMM: 256x256 tile, 512 thr, 64KB dbuf (2 blk/CU) ----------------
__global__ void __launch_bounds__(512, 2) gemm_kernel(
        const int8_t* __restrict__ Xq,       // [M][K]
        const int8_t* __restrict__ Wq,       // [N][K]
        const float* __restrict__ scales,    // [1]
        const float* __restrict__ bias,      // [N]
        const float* __restrict__ row_scale, // [M]
        const float* __restrict__ xabf,      // [M][16] f32
        const __bf16* __restrict__ Blbt,     // [N][16]
        float* __restrict__ out) {           // [M][N]
    // dbuf: S0: A@0 (16K), B@16K; S1: A@32K, B@48K. Total 64 KB -> 2 blocks/CU.
    __shared__ __align__(16) char smem[65536];

    const int tid = threadIdx.x;             // 0..511
    const int wave = tid >> 6, lane = tid & 63;
    const int wm = wave >> 2, wn = wave & 3; // 2 x 4 wave grid
    const int quad = lane >> 4, l16 = lane & 15;

    // XCD swizzle: 512 blocks, 64/XCD; each XCD = contiguous 4-bm stripe x 16 bn
    const int bid = blockIdx.y * gridDim.x + blockIdx.x;  // 0..511
    const int xcd = bid & 7;
    const int local = bid >> 3;                           // 0..63
    const int bm = xcd * 4 + (local >> 4);                // 0..31
    const int bn = local & 15;                            // 0..15

    // staging: per thread 2 slots per operand. slot c: q = c*2 + (tid>>8),
    // row = tid & 255; LDS dst = q*4096 + row*16 = c*8192 + tid*16 (linear).
    const size_t a_base0 = (size_t)(bm * 256 + (tid & 255)) * Kdim + (tid >> 8) * 16;
    const size_t a_base1 = a_base0 + 32;
    const size_t b_base0 = (size_t)(bn * 256 + (tid & 255)) * Kdim + (tid >> 8) * 16;
    const size_t b_base1 = b_base0 + 32;
    const int dst0 = tid * 16, dst1 = 8192 + tid * 16;

    // ds_read bases: addr = q*4096 + row*16 (+ frag*256)
    const int qplane = quad * 4096;
    const int arowb = (wm * 128 + l16) * 16;
    const int browb = (wn * 64 + l16) * 16;

    i32x4 acc[8][4];
#pragma unroll
    for (int i = 0; i < 8; ++i)
#pragma unroll
        for (int j = 0; j < 4; ++j) acc[i][j] = i32x4{0, 0, 0, 0};

    char* const S0 = smem;
    char* const S1 = smem + 32768;

    auto stage = [&](int k0, char* buf) {
        char* PB = buf + 16384;
        async_copy16(Xq + a_base0 + k0, buf + dst0);
        async_copy16(Xq + a_base1 + k0, buf + dst1);
        async_copy16(Wq + b_base0 + k0, PB + dst0);
        async_copy16(Wq + b_base1 + k0, PB + dst1);
    };
    auto compute = [&](const char* buf) {
        const char* PB = buf + 16384;
#pragma unroll
        for (int qd = 0; qd < 4; ++qd) {
            const int i0 = (qd & 1) * 4, j0 = (qd >> 1) * 2;
            i32x4 aF[4], bF[2];
#pragma unroll
            for (int ii = 0; ii < 4; ++ii)
                aF[ii] = *(const i32x4*)(buf + qplane + arowb + (i0 + ii) * 256);
#pragma unroll
            for (int jj = 0; jj < 2; ++jj)
                bF[jj] = *(const i32x4*)(PB + qplane + browb + (j0 + jj) * 256);
            __builtin_amdgcn_s_setprio(1);
#pragma unroll
            for (int ii = 0; ii < 4; ++ii)
#pragma unroll
                for (int jj = 0; jj < 2; ++jj)
                    acc[i0 + ii][j0 + jj] = __builtin_amdgcn_mfma_i32_16x16x64_i8(
                        aF[ii], bF[jj], acc[i0 + ii][j0 + jj], 0, 0, 0);
            __builtin_amdgcn_s_setprio(0);
        }
    };

    // 64 K-tiles of 64. Prologue: tile 0 into S0.
    stage(0, S0);
#pragma unroll 1
    for (int u = 0; u < 31; ++u) {         // tiles 2u, 2u+1 (0..61)
        const int k = u * 128;
        stage(k + 64, S1);                 // tile 2u+1
        ASM_VMCNT4;                        // tile 2u landed; 2u+1 in flight
        __builtin_amdgcn_s_barrier();
        compute(S0);                       // tile 2u
        __builtin_amdgcn_s_barrier();
        stage(k + 128, S0);                // tile 2u+2
        ASM_VMCNT4;
        __builtin_amdgcn_s_barrier();
        compute(S1);                       // tile 2u+1
        __builtin_amdgcn_s_barrier();
    }
    // computed through 61; staged through 62 (S0)
    stage(63 * 64, S1);                    // tile 63
    ASM_VMCNT4;
    __builtin_amdgcn_s_barrier();
    compute(S0);                           // tile 62
    __builtin_amdgcn_s_barrier();
    ASM_VMCNT0;
    __builtin_amdgcn_s_barrier();
    compute(S1);                           // tile 63

    // -------- epilogue: lora (bf16 MFMA, K=16 zero-padded) + bias + dequant --------
    const float wsc = scales[0];
    float bj4[4];
#pragma unroll
    for (int j = 0; j < 4; ++j) bj4[j] = bias[bn * 256 + wn * 64 + j * 16 + l16];

    __syncthreads();  // all waves done with LDS
    // sXAf [256][16] f32 @0 (16KB); sBL bf16 [256][16] @16384 (8KB); sRS @24576 (1KB)
    async_copy16((const char*)xabf + (size_t)bm * 256 * 64 + tid * 16, smem + tid * 16);
    async_copy16((const char*)xabf + (size_t)bm * 256 * 64 + 8192 + tid * 16,
                 smem + 8192 + tid * 16);
    async_copy16((const char*)(Blbt + (size_t)bn * 256 * 16) + tid * 16,
                 smem + 16384 + tid * 16);
    if (tid < 64)
        async_copy16((const char*)(row_scale + bm * 256) + tid * 16,
                     smem + 24576 + tid * 16);
    __syncthreads();

    const float*  sXAf = (const float*)smem;            // [256][16]
    const __bf16* sBL  = (const __bf16*)(smem + 16384); // [256 cols][16]
    const float*  sRS  = (const float*)(smem + 24576);  // [256]

    bf16x8 zf;
#pragma unroll
    for (int k = 0; k < 8; ++k) zf[k] = (__bf16)0.f;

    bf16x8 aF2[8], bF2[4];
#pragma unroll
    for (int i = 0; i < 8; ++i) {
        if (quad < 2) {
            const float* p = sXAf + (wm * 128 + i * 16 + l16) * 16 + quad * 8;
            f32x4 u0 = *(const f32x4*)p;
            f32x4 u1 = *(const f32x4*)(p + 4);
            bf16x8 t;
            t[0] = (__bf16)u0[0]; t[1] = (__bf16)u0[1];
            t[2] = (__bf16)u0[2]; t[3] = (__bf16)u0[3];
            t[4] = (__bf16)u1[0]; t[5] = (__bf16)u1[1];
            t[6] = (__bf16)u1[2]; t[7] = (__bf16)u1[3];
            aF2[i] = t;
        } else {
            aF2[i] = zf;
        }
    }
#pragma unroll
    for (int j = 0; j < 4; ++j) {
        if (quad < 2) bF2[j] = *(const bf16x8*)(sBL + (wn * 64 + j * 16 + l16) * 16 + quad * 8);
        else          bF2[j] = zf;
    }

    const int col0 = bn * 256 + wn * 64 + l16;
#pragma unroll
    for (int i = 0; i < 8; ++i) {
#pragma unroll
        for (int j = 0; j < 4; ++j) {
            f32x4 l = f32x4{bj4[j], bj4[j], bj4[j], bj4[j]};
            l = __builtin_amdgcn_mfma_f32_16x16x32_bf16(aF2[i], bF2[j], l, 0, 0, 0);
            const int col = col0 + j * 16;
            const int lr = wm * 128 + i * 16 + quad * 4;  // row in block-tile
#pragma unroll
            for (int r = 0; r < 4; ++r) {
                float sx = sRS[lr + r] * wsc;
                out[(size_t)(bm * 256 + lr + r) * Ndim + col] =
                    (float)acc[i][j][r] * sx + l[r];
            }
        }
    }
}

extern "C" void kernel_launch(void* const* d_in, const int* in_sizes, int n_in,
                              void* d_out, int out_size, void* d_ws, size_t ws_size,
                              hipStream_t stream) {
    const float* x      = (const float*)d_in[0];
    const int*   qw     = (const int*)d_in[1];
    const float* scales = (const float*)d_in[2];
    const float* bias   = (const float*)d_in[3];
    const float* lA     = (const float*)d_in[4];
    const float* lB     = (const float*)d_in[5];
    float* out = (float*)d_out;

    char* ws = (char*)d_ws;
    int8_t* x_i8     = (int8_t*)ws;                     // 33.55 MB
    int8_t* w_i8     = (int8_t*)(ws + 33554432);        // 16.78 MB
    int8_t* a_i8t    = (int8_t*)(ws + 50331648);        // 64 KB
    float*  xabf     = (float*)(ws + 50397184);         // 512 KB f32 [M][16]
    __bf16* Blbt     = (__bf16*)(ws + 50921472);        // 128 KB
    float*  row_scale = (float*)(ws + 51052544);        // 32 KB
    float*  a_scale_g = (float*)(ws + 51085312);        // 4 B

    const int prep_blocks = 1 + BLK_W + BLK_X + BLK_BT;  // 12305
    prep_kernel<<<prep_blocks, 256, 0, stream>>>(
        x, qw, lA, lB, x_i8, w_i8, a_i8t, Blbt, row_scale, a_scale_g, xabf);
    xa_kernel<<<512, 256, 0, stream>>>(x_i8, a_i8t, row_scale, a_scale_g, xabf);
    dim3 grid(Ndim / 256, Mdim / 256);                   // 16 x 32 = 512 blocks
    gemm_kernel<<<grid, 512, 0, stream>>>(x_i8, w_i8, scales, bias, row_scale,
                                          xabf, Blbt, out);
}